// Round 1
// baseline (1454.784 us; speedup 1.0000x reference)
//
#include <hip/hip_runtime.h>
#include <hip/hip_bf16.h>
#include <stdint.h>

// Problem constants (from reference setup_inputs)
#define B_  64
#define LA  512
#define LB  512
#define DD  768
#define NEGV -100000.0f

typedef __attribute__((ext_vector_type(8))) short bf16x8;
typedef __attribute__((ext_vector_type(4))) float f32x4;

__device__ __forceinline__ unsigned short f2bf(float x) {
    union { float f; unsigned u; } v; v.f = x;
    unsigned r = v.u + 0x7fffu + ((v.u >> 16) & 1u);   // RNE
    return (unsigned short)(r >> 16);
}
__device__ __forceinline__ float bf2f(unsigned short h) {
    union { float f; unsigned u; } v; v.u = ((unsigned)h) << 16;
    return v.f;
}

// ---------------------------------------------------------------------------
// Transpose + convert: x [B, L, Dm] fp32  ->  xT [B, Dm, L] bf16
// grid (L/64, Dm/64, B), block 256
// ---------------------------------------------------------------------------
template<int L, int Dm>
__global__ void conv_transpose_k(const float* __restrict__ x,
                                 unsigned short* __restrict__ xT) {
    __shared__ unsigned short tile[64][65];
    const int l0 = blockIdx.x * 64, d0 = blockIdx.y * 64, b = blockIdx.z;
    const float* xp = x + (size_t)b * L * Dm;
    unsigned short* op = xT + (size_t)b * Dm * L;
    const int c = threadIdx.x & 63, r0 = threadIdx.x >> 6;
#pragma unroll
    for (int s = 0; s < 16; ++s) {
        int r = r0 + s * 4;
        tile[r][c] = f2bf(xp[(size_t)(l0 + r) * Dm + d0 + c]);
    }
    __syncthreads();
#pragma unroll
    for (int s = 0; s < 16; ++s) {
        int r = r0 + s * 4;
        op[(size_t)(d0 + r) * L + l0 + c] = tile[c][r];
    }
}

// ---------------------------------------------------------------------------
// e = a . b^T  per batch, fp32-accurate via bf16x3 split MFMA; mask applied.
// grid (LA/128, LB/128, B), block 256 (4 waves, 2x2 of 64x64)
// ---------------------------------------------------------------------------
__global__ __launch_bounds__(256, 2)
void egemm_k(const float* __restrict__ a, const float* __restrict__ b,
             const int* __restrict__ mask_a, const int* __restrict__ mask_b,
             float* __restrict__ e) {
    constexpr int BK = 32, STR = 40;   // 32 + 8 pad (ushort units)
    __shared__ unsigned short Ah[128 * STR], Al[128 * STR];
    __shared__ unsigned short Bh[128 * STR], Bl[128 * STR];

    const int m0 = blockIdx.x * 128, n0 = blockIdx.y * 128, bb = blockIdx.z;
    const float* ap = a + (size_t)bb * LA * DD;
    const float* bp = b + (size_t)bb * LB * DD;
    const int tid = threadIdx.x;
    const int lane = tid & 63, w = tid >> 6;
    const int wm = (w >> 1) * 64, wn = (w & 1) * 64;
    const int lrow = lane & 15, lk = (lane >> 4) * 8;

    f32x4 acc[4][4] = {};

    const int srow = tid >> 3;            // 0..31
    const int scol = (tid & 7) * 4;       // 0..28 step 4

    for (int k0 = 0; k0 < DD; k0 += BK) {
        __syncthreads();
#pragma unroll
        for (int s = 0; s < 4; ++s) {
            int r = srow + s * 32;
            float4 va = *(const float4*)(ap + (size_t)(m0 + r) * DD + k0 + scol);
            float4 vb = *(const float4*)(bp + (size_t)(n0 + r) * DD + k0 + scol);
            ushort4 h, l;
            h.x = f2bf(va.x); l.x = f2bf(va.x - bf2f(h.x));
            h.y = f2bf(va.y); l.y = f2bf(va.y - bf2f(h.y));
            h.z = f2bf(va.z); l.z = f2bf(va.z - bf2f(h.z));
            h.w = f2bf(va.w); l.w = f2bf(va.w - bf2f(h.w));
            *(ushort4*)&Ah[r * STR + scol] = h;
            *(ushort4*)&Al[r * STR + scol] = l;
            h.x = f2bf(vb.x); l.x = f2bf(vb.x - bf2f(h.x));
            h.y = f2bf(vb.y); l.y = f2bf(vb.y - bf2f(h.y));
            h.z = f2bf(vb.z); l.z = f2bf(vb.z - bf2f(h.z));
            h.w = f2bf(vb.w); l.w = f2bf(vb.w - bf2f(h.w));
            *(ushort4*)&Bh[r * STR + scol] = h;
            *(ushort4*)&Bl[r * STR + scol] = l;
        }
        __syncthreads();

        bf16x8 ahf[4], alf[4], bhf[4], blf[4];
#pragma unroll
        for (int mi = 0; mi < 4; ++mi) {
            int r = wm + mi * 16 + lrow;
            ahf[mi] = *(const bf16x8*)&Ah[r * STR + lk];
            alf[mi] = *(const bf16x8*)&Al[r * STR + lk];
        }
#pragma unroll
        for (int ni = 0; ni < 4; ++ni) {
            int r = wn + ni * 16 + lrow;
            bhf[ni] = *(const bf16x8*)&Bh[r * STR + lk];
            blf[ni] = *(const bf16x8*)&Bl[r * STR + lk];
        }
#pragma unroll
        for (int mi = 0; mi < 4; ++mi)
#pragma unroll
            for (int ni = 0; ni < 4; ++ni) {
                acc[mi][ni] = __builtin_amdgcn_mfma_f32_16x16x32_bf16(alf[mi], bhf[ni], acc[mi][ni], 0, 0, 0);
                acc[mi][ni] = __builtin_amdgcn_mfma_f32_16x16x32_bf16(ahf[mi], blf[ni], acc[mi][ni], 0, 0, 0);
                acc[mi][ni] = __builtin_amdgcn_mfma_f32_16x16x32_bf16(ahf[mi], bhf[ni], acc[mi][ni], 0, 0, 0);
            }
    }

    // epilogue: mask + store e
    const int* map = mask_a + bb * LA;
    const int* mbp = mask_b + bb * LB;
    float* ep = e + (size_t)bb * LA * LB;
    const int colbase = n0 + wn + (lane & 15);
    const int rowbase = m0 + wm + (lane >> 4) * 4;
#pragma unroll
    for (int mi = 0; mi < 4; ++mi) {
#pragma unroll
        for (int ni = 0; ni < 4; ++ni) {
            int j = colbase + ni * 16;
            float mbf = (float)mbp[j];
#pragma unroll
            for (int r = 0; r < 4; ++r) {
                int i = rowbase + mi * 16 + r;
                float mm = (float)map[i] * mbf;
                float v = (mm < 0.5f) ? NEGV : acc[mi][ni][r];
                ep[(size_t)i * LB + j] = v;
            }
        }
    }
}

// ---------------------------------------------------------------------------
// Row softmax stats (axis=2): one wave per row of e. Stores max and 1/sum.
// grid B*LA/4, block 256
// ---------------------------------------------------------------------------
__global__ void rowstats_k(const float* __restrict__ e,
                           float* __restrict__ rmax, float* __restrict__ rinv) {
    const int row = blockIdx.x * 4 + (threadIdx.x >> 6);
    const int lane = threadIdx.x & 63;
    const float* ep = e + (size_t)row * LB;
    float4 v1 = *(const float4*)(ep + lane * 8);
    float4 v2 = *(const float4*)(ep + lane * 8 + 4);
    float m = fmaxf(fmaxf(fmaxf(v1.x, v1.y), fmaxf(v1.z, v1.w)),
                    fmaxf(fmaxf(v2.x, v2.y), fmaxf(v2.z, v2.w)));
#pragma unroll
    for (int o = 32; o; o >>= 1) m = fmaxf(m, __shfl_xor(m, o));
    float s = __expf(v1.x - m) + __expf(v1.y - m) + __expf(v1.z - m) + __expf(v1.w - m)
            + __expf(v2.x - m) + __expf(v2.y - m) + __expf(v2.z - m) + __expf(v2.w - m);
#pragma unroll
    for (int o = 32; o; o >>= 1) s += __shfl_xor(s, o);
    if (lane == 0) { rmax[row] = m; rinv[row] = 1.0f / s; }
}

// ---------------------------------------------------------------------------
// Column softmax stats (axis=1): one thread per column j. Stores max, 1/sum.
// grid (LB/256, B), block 256
// ---------------------------------------------------------------------------
__global__ void colstats_k(const float* __restrict__ e,
                           float* __restrict__ cmax, float* __restrict__ cinv) {
    const int j = blockIdx.x * 256 + threadIdx.x;
    const int bb = blockIdx.y;
    const float* ep = e + (size_t)bb * LA * LB + j;
    float m0 = -3.4e38f, m1 = -3.4e38f, m2 = -3.4e38f, m3 = -3.4e38f;
    for (int i = 0; i < LA; i += 4) {
        m0 = fmaxf(m0, ep[(size_t)(i + 0) * LB]);
        m1 = fmaxf(m1, ep[(size_t)(i + 1) * LB]);
        m2 = fmaxf(m2, ep[(size_t)(i + 2) * LB]);
        m3 = fmaxf(m3, ep[(size_t)(i + 3) * LB]);
    }
    float m = fmaxf(fmaxf(m0, m1), fmaxf(m2, m3));
    float s0 = 0.f, s1 = 0.f, s2 = 0.f, s3 = 0.f;
    for (int i = 0; i < LA; i += 4) {
        s0 += __expf(ep[(size_t)(i + 0) * LB] - m);
        s1 += __expf(ep[(size_t)(i + 1) * LB] - m);
        s2 += __expf(ep[(size_t)(i + 2) * LB] - m);
        s3 += __expf(ep[(size_t)(i + 3) * LB] - m);
    }
    cmax[bb * LB + j] = m;
    cinv[bb * LB + j] = 1.0f / (s0 + s1 + s2 + s3);
}

// ---------------------------------------------------------------------------
// P generation: Pa[b,i,j] = softmax_axis2(e) bf16 ; PbT[b,j,i] = softmax_axis1(e) bf16
// grid (LA/64, LB/64, B), block 256
// ---------------------------------------------------------------------------
__global__ void pgen_k(const float* __restrict__ e,
                       const float* __restrict__ rmax, const float* __restrict__ rinv,
                       const float* __restrict__ cmax, const float* __restrict__ cinv,
                       unsigned short* __restrict__ Pa, unsigned short* __restrict__ PbT) {
    __shared__ unsigned short tile[64][65];
    const int i0 = blockIdx.x * 64, j0 = blockIdx.y * 64, bb = blockIdx.z;
    const float* ep = e + (size_t)bb * LA * LB;
    const int c = threadIdx.x & 63, r0 = threadIdx.x >> 6;
    const float cm = cmax[bb * LB + j0 + c];
    const float ci = cinv[bb * LB + j0 + c];
#pragma unroll
    for (int s = 0; s < 16; ++s) {
        int r = r0 + s * 4;
        float rm = rmax[bb * LA + i0 + r];
        float ri = rinv[bb * LA + i0 + r];
        float v = ep[(size_t)(i0 + r) * LB + j0 + c];
        Pa[((size_t)bb * LA + i0 + r) * LB + j0 + c] = f2bf(__expf(v - rm) * ri);
        tile[r][c] = f2bf(__expf(v - cm) * ci);
    }
    __syncthreads();
#pragma unroll
    for (int s = 0; s < 16; ++s) {
        int r = r0 + s * 4;
        PbT[((size_t)bb * LB + j0 + r) * LA + i0 + c] = tile[c][r];
    }
}

// ---------------------------------------------------------------------------
// t = P . V, fused concat epilogue:  out[b,i,:] = [x, t, x-t, x*t]
//   P  : [B, M, K] bf16 row-major (M=512, K=512)
//   VT : [B, N, K] bf16 row-major (N=DD) -- V transposed so K is contiguous
//   X  : [B, M, DD] fp32 (a or b)
//   out: [B, M, 4*DD] fp32
// grid (M/128, DD/128, B), block 256
// ---------------------------------------------------------------------------
__global__ __launch_bounds__(256, 2)
void pv_gemm_k(const unsigned short* __restrict__ P,
               const unsigned short* __restrict__ VT,
               const float* __restrict__ X,
               float* __restrict__ out) {
    constexpr int M = 512, K = 512, STR = 40;
    __shared__ unsigned short At[128 * STR], Bt[128 * STR];

    const int m0 = blockIdx.x * 128, n0 = blockIdx.y * 128, bb = blockIdx.z;
    const unsigned short* Pp = P + (size_t)bb * M * K;
    const unsigned short* Vp = VT + (size_t)bb * DD * K;
    const int tid = threadIdx.x;
    const int lane = tid & 63, w = tid >> 6;
    const int wm = (w >> 1) * 64, wn = (w & 1) * 64;
    const int lrow = lane & 15, lk = (lane >> 4) * 8;

    f32x4 acc[4][4] = {};

    for (int k0 = 0; k0 < K; k0 += 32) {
        __syncthreads();
#pragma unroll
        for (int s = 0; s < 2; ++s) {
            int ch = tid + s * 256;           // 0..511
            int row = ch >> 2;                // 0..127
            int c = (ch & 3) * 8;             // ushort offset 0..24
            uint4 va = *(const uint4*)(Pp + (size_t)(m0 + row) * K + k0 + c);
            *(uint4*)&At[row * STR + c] = va;
            uint4 vb = *(const uint4*)(Vp + (size_t)(n0 + row) * K + k0 + c);
            *(uint4*)&Bt[row * STR + c] = vb;
        }
        __syncthreads();

        bf16x8 af[4], bf[4];
#pragma unroll
        for (int mi = 0; mi < 4; ++mi)
            af[mi] = *(const bf16x8*)&At[(wm + mi * 16 + lrow) * STR + lk];
#pragma unroll
        for (int ni = 0; ni < 4; ++ni)
            bf[ni] = *(const bf16x8*)&Bt[(wn + ni * 16 + lrow) * STR + lk];
#pragma unroll
        for (int mi = 0; mi < 4; ++mi)
#pragma unroll
            for (int ni = 0; ni < 4; ++ni)
                acc[mi][ni] = __builtin_amdgcn_mfma_f32_16x16x32_bf16(af[mi], bf[ni], acc[mi][ni], 0, 0, 0);
    }

    // fused epilogue: out[b,i, d]=x, [DD+d]=t, [2DD+d]=x-t, [3DD+d]=x*t
    const float* Xp = X + (size_t)bb * M * DD;
    float* op = out + (size_t)bb * M * (4 * DD);
    const int colbase = n0 + wn + (lane & 15);
    const int rowbase = m0 + wm + (lane >> 4) * 4;
#pragma unroll
    for (int mi = 0; mi < 4; ++mi) {
#pragma unroll
        for (int ni = 0; ni < 4; ++ni) {
            int d = colbase + ni * 16;
#pragma unroll
            for (int r = 0; r < 4; ++r) {
                int i = rowbase + mi * 16 + r;
                float t = acc[mi][ni][r];
                float x = Xp[(size_t)i * DD + d];
                float* o = op + (size_t)i * (4 * DD) + d;
                o[0]      = x;
                o[DD]     = t;
                o[2 * DD] = x - t;
                o[3 * DD] = x * t;
            }
        }
    }
}

// ---------------------------------------------------------------------------
extern "C" void kernel_launch(void* const* d_in, const int* in_sizes, int n_in,
                              void* d_out, int out_size, void* d_ws, size_t ws_size,
                              hipStream_t stream) {
    const float* a      = (const float*)d_in[0];
    const int*   mask_a = (const int*)d_in[1];
    const float* b      = (const float*)d_in[2];
    const int*   mask_b = (const int*)d_in[3];
    float* out = (float*)d_out;

    uint8_t* w = (uint8_t*)d_ws;
    float* e            = (float*)w;          w += (size_t)B_ * LA * LB * 4;   // 67.1 MB
    unsigned short* Pa  = (unsigned short*)w; w += (size_t)B_ * LA * LB * 2;   // 33.6 MB
    unsigned short* PbT = (unsigned short*)w; w += (size_t)B_ * LB * LA * 2;   // 33.6 MB
    unsigned short* bT  = (unsigned short*)w; w += (size_t)B_ * DD * LB * 2;   // 50.3 MB
    unsigned short* aT  = (unsigned short*)w; w += (size_t)B_ * DD * LA * 2;   // 50.3 MB
    float* rmax = (float*)w; w += (size_t)B_ * LA * 4;
    float* rinv = (float*)w; w += (size_t)B_ * LA * 4;
    float* cmax = (float*)w; w += (size_t)B_ * LB * 4;
    float* cinv = (float*)w; w += (size_t)B_ * LB * 4;
    // total ~236 MB

    conv_transpose_k<LA, DD><<<dim3(LA / 64, DD / 64, B_), 256, 0, stream>>>(a, aT);
    conv_transpose_k<LB, DD><<<dim3(LB / 64, DD / 64, B_), 256, 0, stream>>>(b, bT);
    egemm_k<<<dim3(LA / 128, LB / 128, B_), 256, 0, stream>>>(a, b, mask_a, mask_b, e);
    rowstats_k<<<B_ * LA / 4, 256, 0, stream>>>(e, rmax, rinv);
    colstats_k<<<dim3(LB / 256, B_), 256, 0, stream>>>(e, cmax, cinv);
    pgen_k<<<dim3(LA / 64, LB / 64, B_), 256, 0, stream>>>(e, rmax, rinv, cmax, cinv, Pa, PbT);
    float* out_mb = out + (size_t)B_ * LA * (4 * DD);
    pv_gemm_k<<<dim3(512 / 128, DD / 128, B_), 256, 0, stream>>>(Pa, bT, a, out);
    pv_gemm_k<<<dim3(512 / 128, DD / 128, B_), 256, 0, stream>>>(PbT, aT, b, out_mb);
}